// Round 13
// baseline (211.724 us; speedup 1.0000x reference)
//
#include <hip/hip_runtime.h>
#include <hip/hip_bf16.h>

// T=5 B=512 NA=16 S=64 A=16 HID=64 H=4 FD=256 LAT=128 N=8192 FIN=80
// Inputs fp32, output fp32. edge graph = complete per 16-agent batch (ignored
// input). seq = x[::16] (dst agent-0 only). attention query only at t=4.
//
// R13 vs R12 (205 us): kernels sum to ~105 us -> ~100 us is launch/boundary
// overhead. stage2(b) depends only on gat-block(b)'s seq rows -> FUSE gat +
// stage2 into one block-per-b kernel; seq stays in LDS (no global round-trip,
// one less launch). Stage2 LDS overlays dead GAT arrays (kL/vL over u1/ud1,
// q/ctx/feat over a0g, belief over dL); total 75232 B -> still 2 blocks/CU.
// u1L padded 256->260 (kills 4-way bank conflict in es1 phase).

__device__ __forceinline__ float wave_sum64(float v) {
    #pragma unroll
    for (int off = 32; off > 0; off >>= 1) v += __shfl_xor(v, off, 64);
    return v;
}
__device__ __forceinline__ float wave_max64(float v) {
    #pragma unroll
    for (int off = 32; off > 0; off >>= 1) v = fmaxf(v, __shfl_xor(v, off, 64));
    return v;
}

// ---------------- prologue: transposes + u1/ud1/pa0/pd0 (merged) ------------
// blocks 0..1679: transposes into tws; block 1680: attention-vector folds.
__global__ __launch_bounds__(256) void k_pre(
    const float* __restrict__ w0, const float* __restrict__ w1,
    const float* __restrict__ wip, const float* __restrict__ wop,
    const float* __restrict__ wm, const float* __restrict__ wlv,
    const float* __restrict__ wb,
    const float* __restrict__ as0, const float* __restrict__ ad0,
    const float* __restrict__ as1, const float* __restrict__ ad1,
    float* __restrict__ tws,
    float* __restrict__ u1, float* __restrict__ ud1,
    float* __restrict__ pa0, float* __restrict__ pd0)
{
    const int tid = threadIdx.x;
    if (blockIdx.x < 1680) {
        int i = blockIdx.x * 256 + tid;          // 1680*256 = 430080 exact
        float v;
        if (i < 16384) {                         // W0sT[k][n] = w0[n][k]
            int k = i >> 8, n = i & 255;
            v = w0[n * 80 + k];
        } else if (i < 20480) {                  // W0aT[k][n] = w0[n][64+k]
            int j = i - 16384; int k = j >> 8, n = j & 255;
            v = w0[n * 80 + 64 + k];
        } else if (i < 86016) {                  // W1T[k][n] = w1[n][k]
            int j = i - 20480; int k = j >> 8, n = j & 255;
            v = w1[n * 256 + k];
        } else if (i < 282624) {                 // wipT[k][n'] = wip[n'][k]
            int j = i - 86016; int k = j / 768, n = j - k * 768;
            v = wip[n * 256 + k];
        } else if (i < 348160) {                 // wopT[k][n] = wop[n][k]
            int j = i - 282624; int k = j >> 8, n = j & 255;
            v = wop[n * 256 + k];
        } else {                                 // whT[k][j]: mean|logvar|belief
            int j = i - 348160; int k = j / 320, o = j - k * 320;
            if (o < 128)      v = wm[o * 256 + k];
            else if (o < 256) v = wlv[(o - 128) * 256 + k];
            else              v = wb[(o - 256) * 256 + k];
        }
        tws[i] = v;
        return;
    }
    // block 1680: u1[h][k] = sum_c as1[h][c]*w1[(h*64+c)][k]; ud1 with ad1
    for (int q = 0; q < 4; q++) {
        int idx = q * 256 + tid;                 // 1024
        int h = idx >> 8, k = idx & 255;
        float su = 0.f, sd = 0.f;
        for (int c = 0; c < 64; c++) {
            float wv = w1[(h * 64 + c) * 256 + k];
            su = fmaf(as1[h * 64 + c], wv, su);
            sd = fmaf(ad1[h * 64 + c], wv, sd);
        }
        u1[idx] = su; ud1[idx] = sd;
    }
    if (tid < 64) {
        int h = tid >> 4, k = tid & 15;
        float su = 0.f, sd = 0.f;
        for (int c = 0; c < 64; c++) {
            float wv = w0[(h * 64 + c) * 80 + 64 + k];
            su = fmaf(as0[h * 64 + c], wv, su);
            sd = fmaf(ad0[h * 64 + c], wv, sd);
        }
        pa0[tid] = su; pd0[tid] = sd;
    }
}

// ---------------- fused: 2-layer GAT + qkv + attention + out_proj + heads ---
// One block per batch b, 256 threads. LDS blob with stage2 overlays.
__global__ __launch_bounds__(256) void k_fused(
    const float* __restrict__ sig,   // (T,B,64)
    const float* __restrict__ nact,  // (T,B,256)
    const float* __restrict__ W0sT, const float* __restrict__ W0aT,
    const float* __restrict__ W1T,
    const float* __restrict__ u1g, const float* __restrict__ ud1g,
    const float* __restrict__ pa0g, const float* __restrict__ pd0g,
    const float* __restrict__ as0, const float* __restrict__ ad0,
    const float* __restrict__ b0, const float* __restrict__ b1,
    const float* __restrict__ wipT,  // [256][768]
    const float* __restrict__ bip,
    const float* __restrict__ wopT,  // [256][256]
    const float* __restrict__ bop,
    const float* __restrict__ whT,   // [256][320]
    const float* __restrict__ bm, const float* __restrict__ blv,
    const float* __restrict__ bb,
    float* __restrict__ out)
{
    __shared__ __align__(16) char smem[75232];
    float* sigL   = (float*)(smem + 0);        // [5][64]
    float* actL   = (float*)(smem + 1280);     // [5][16][16]
    float* SL     = (float*)(smem + 6400);     // [5][258]
    float* u1L    = (float*)(smem + 11560);    // [4][260] (pad: bank-safe)
    float* ud1L   = (float*)(smem + 15720);    // [4][260]
    float* pa0L   = (float*)(smem + 19880);    // [64]
    float* pd0L   = (float*)(smem + 20136);    // [64]
    float* sSL    = (float*)(smem + 20392);    // [5][4]
    float* dSL    = (float*)(smem + 20472);    // [5][4]
    float* es0L   = (float*)(smem + 20552);    // [5][16][4]
    float* ed0L   = (float*)(smem + 21832);    // [5][16][4]
    float* a0g    = (float*)(smem + 23112);    // [4][16][16]
    float* dL     = (float*)(smem + 27208);    // [4][16][16]
    float* x1L    = (float*)(smem + 31304);    // [16][258]
    float* espL   = (float*)(smem + 47816);    // [16][4][4]
    float* edpL   = (float*)(smem + 48840);    // [4][4]
    float* es1L   = (float*)(smem + 48904);    // [16][4]
    float* edL    = (float*)(smem + 49160);    // [4]
    float* alpha1L= (float*)(smem + 49176);    // [4][16]
    float* zL     = (float*)(smem + 49432);    // [5][4][258]
    float* sseq   = (float*)(smem + 70072);    // [5][258]
    // stage2 overlays (regions dead after the g-loop):
    float* kLp    = (float*)(smem + 11560);    // [5][256] over u1L+
    float* vLp    = (float*)(smem + 16680);    // [5][256] over ud1L-tail..es0L
    float* qLp    = (float*)(smem + 23112);    // [256] over a0g
    float* ctxLp  = (float*)(smem + 24136);    // [256]
    float* featLp = (float*)(smem + 25160);    // [256]
    float* belLp  = (float*)(smem + 27208);    // [64] over dL

    const int tid = threadIdx.x;
    const int b = blockIdx.x;

    // ---- load inputs + precomputed small tensors
    for (int i = tid; i < 320; i += 256)
        sigL[i] = sig[((i >> 6) * 512 + b) * 64 + (i & 63)];
    for (int i = tid; i < 1280; i += 256)
        actL[i] = nact[((i >> 8) * 512 + b) * 256 + (i & 255)];
    #pragma unroll
    for (int q = 0; q < 4; q++) {
        int idx = q * 256 + tid;
        int h = idx >> 8, k = idx & 255;
        u1L[h * 260 + k] = u1g[idx];
        ud1L[h * 260 + k] = ud1g[idx];
    }
    if (tid < 64) { pa0L[tid] = pa0g[tid]; pd0L[tid] = pd0g[tid]; }
    __syncthreads();

    // ---- S[g][n] = sum_k sig[g][k] * W0sT[k][n]
    {
        const int n = tid;
        float acc[5] = {0, 0, 0, 0, 0};
        for (int k = 0; k < 64; k++) {
            float wv = W0sT[k * 256 + n];
            #pragma unroll
            for (int g = 0; g < 5; g++) acc[g] = fmaf(sigL[g * 64 + k], wv, acc[g]);
        }
        #pragma unroll
        for (int g = 0; g < 5; g++) SL[g * 258 + n] = acc[g];
    }
    __syncthreads();

    // ---- sS/dS[g][h]
    if (tid < 20) {
        int g = tid / 4, h = tid & 3;
        float su = 0.f, sd = 0.f;
        for (int c = 0; c < 64; c++) {
            float sv = SL[g * 258 + h * 64 + c];
            su = fmaf(sv, as0[h * 64 + c], su);
            sd = fmaf(sv, ad0[h * 64 + c], sd);
        }
        sSL[g * 4 + h] = su; dSL[g * 4 + h] = sd;
    }
    __syncthreads();

    // ---- es0/ed0[g][m][h] = (m==0)*sS/dS + act[g][m] . pa0/pd0[h]
    for (int q = tid; q < 320; q += 256) {
        int g = q >> 6, r = q & 63, m = r >> 2, h = r & 3;
        float su = (m == 0) ? sSL[g * 4 + h] : 0.f;
        float sd = (m == 0) ? dSL[g * 4 + h] : 0.f;
        #pragma unroll
        for (int k = 0; k < 16; k++) {
            float av = actL[g * 256 + m * 16 + k];
            su = fmaf(av, pa0L[h * 16 + k], su);
            sd = fmaf(av, pd0L[h * 16 + k], sd);
        }
        es0L[g * 64 + m * 4 + h] = su; ed0L[g * 64 + m * 4 + h] = sd;
    }
    __syncthreads();

    // ================= per t-group loop =================
    for (int g = 0; g < 5; g++) {
        // alpha0[h][j][s]
        if (tid < 64) {
            int h = tid >> 4, j = tid & 15;
            float ej = ed0L[g * 64 + j * 4 + h];
            float e[16], m = -1e30f;
            #pragma unroll
            for (int s = 0; s < 16; s++) {
                float x = es0L[g * 64 + s * 4 + h] + ej;
                x = (x >= 0.f) ? x : 0.2f * x;
                e[s] = x; m = fmaxf(m, x);
            }
            float sum = 0.f;
            #pragma unroll
            for (int s = 0; s < 16; s++) { e[s] = __expf(e[s] - m); sum += e[s]; }
            float inv = 1.f / sum;
            #pragma unroll
            for (int s = 0; s < 16; s++) a0g[h * 256 + j * 16 + s] = e[s] * inv;
        }
        __syncthreads();

        // d[h][j][k] = sum_s alpha0[h][j][s] * act[s][k]
        #pragma unroll
        for (int q = 0; q < 4; q++) {
            int idx = q * 256 + tid;
            int h = idx >> 8, j = (idx >> 4) & 15, k = idx & 15;
            float a = 0.f;
            #pragma unroll
            for (int s = 0; s < 16; s++)
                a = fmaf(a0g[h * 256 + j * 16 + s], actL[g * 256 + s * 16 + k], a);
            dL[h * 256 + j * 16 + k] = a;
        }
        __syncthreads();

        // x1[j][n] = relu(alpha0[h][j][0]*S[n] + d[h][j] . W0aT[:,n] + b0[n])
        {
            const int n = tid, h = n >> 6;
            float sv = SL[g * 258 + n], b0v = b0[n];
            float accj[16];
            #pragma unroll
            for (int j = 0; j < 16; j++)
                accj[j] = fmaf(a0g[h * 256 + j * 16], sv, b0v);
            #pragma unroll
            for (int k = 0; k < 16; k++) {
                float wv = W0aT[k * 256 + n];
                #pragma unroll
                for (int j = 0; j < 16; j++)
                    accj[j] = fmaf(dL[h * 256 + j * 16 + k], wv, accj[j]);
            }
            #pragma unroll
            for (int j = 0; j < 16; j++)
                x1L[j * 258 + n] = fmaxf(accj[j], 0.f);
        }
        __syncthreads();

        // es1[m][h] = x1[m] . u1[h]; ed1[h] = x1[0] . ud1[h]
        {
            int m = tid >> 4, h = (tid >> 2) & 3, p = tid & 3;
            float a = 0.f;
            for (int kk = 0; kk < 64; kk++) {
                int k = kk * 4 + p;
                a = fmaf(x1L[m * 258 + k], u1L[h * 260 + k], a);
            }
            espL[m * 16 + h * 4 + p] = a;
            if (m == 0) {
                float ad = 0.f;
                for (int kk = 0; kk < 64; kk++) {
                    int k = kk * 4 + p;
                    ad = fmaf(x1L[k], ud1L[h * 260 + k], ad);
                }
                edpL[h * 4 + p] = ad;
            }
        }
        __syncthreads();
        if (tid < 64) {
            int m = tid >> 2, h = tid & 3;
            const float* e = espL + m * 16 + h * 4;
            es1L[m * 4 + h] = e[0] + e[1] + e[2] + e[3];
        }
        if (tid < 4)
            edL[tid] = edpL[tid * 4] + edpL[tid * 4 + 1] + edpL[tid * 4 + 2] + edpL[tid * 4 + 3];
        __syncthreads();

        // alpha1[h][s] (dst agent 0)
        if (tid < 4) {
            int h = tid;
            float ej = edL[h];
            float e[16], m = -1e30f;
            #pragma unroll
            for (int s = 0; s < 16; s++) {
                float x = es1L[s * 4 + h] + ej;
                x = (x >= 0.f) ? x : 0.2f * x;
                e[s] = x; m = fmaxf(m, x);
            }
            float sum = 0.f;
            #pragma unroll
            for (int s = 0; s < 16; s++) { e[s] = __expf(e[s] - m); sum += e[s]; }
            float inv = 1.f / sum;
            #pragma unroll
            for (int s = 0; s < 16; s++) alpha1L[h * 16 + s] = e[s] * inv;
        }
        __syncthreads();

        // z[g][h][k] = sum_s alpha1[h][s] * x1[s][k]
        {
            const int k = tid;
            float xv[16];
            #pragma unroll
            for (int s = 0; s < 16; s++) xv[s] = x1L[s * 258 + k];
            #pragma unroll
            for (int h = 0; h < 4; h++) {
                float zv = 0.f;
                #pragma unroll
                for (int s = 0; s < 16; s++)
                    zv = fmaf(alpha1L[h * 16 + s], xv[s], zv);
                zL[g * 1032 + h * 258 + k] = zv;
            }
        }
        __syncthreads();
    }

    // ---- seq[g][n] = relu(z[g][h(n)] . W1T[:,n] + b1[n])  (to LDS)
    {
        const int n = tid, h = n >> 6;
        float b1v = b1[n];
        float acc[5] = {b1v, b1v, b1v, b1v, b1v};
        for (int k = 0; k < 256; k++) {
            float wv = W1T[k * 256 + n];
            #pragma unroll
            for (int g = 0; g < 5; g++)
                acc[g] = fmaf(zL[g * 1032 + h * 258 + k], wv, acc[g]);
        }
        #pragma unroll
        for (int g = 0; g < 5; g++)
            sseq[g * 258 + n] = fmaxf(acc[g], 0.f);
    }
    __syncthreads();

    // ============ stage 2 (overlays live from here) ============
    // qkv: thread n; q (t=4), k/v all t; coalesced wipT columns
    {
        const int n = tid;
        float accq = 0.f, acck[5] = {0, 0, 0, 0, 0}, accv[5] = {0, 0, 0, 0, 0};
        for (int k = 0; k < 256; k++) {
            float wq = wipT[k * 768 + n];
            float wk = wipT[k * 768 + 256 + n];
            float wv = wipT[k * 768 + 512 + n];
            accq = fmaf(sseq[4 * 258 + k], wq, accq);
            #pragma unroll
            for (int t = 0; t < 5; t++) {
                float sv = sseq[t * 258 + k];
                acck[t] = fmaf(sv, wk, acck[t]);
                accv[t] = fmaf(sv, wv, accv[t]);
            }
        }
        qLp[n] = accq + bip[n];
        float bk = bip[256 + n], bv = bip[512 + n];
        #pragma unroll
        for (int t = 0; t < 5; t++) {
            kLp[t * 256 + n] = acck[t] + bk;
            vLp[t * 256 + n] = accv[t] + bv;
        }
    }
    __syncthreads();

    // attention at q=4 (causal mask constant -> cancels); wave = head
    {
        const int col = tid;
        float q4 = qLp[col];
        float sc[5];
        #pragma unroll
        for (int t = 0; t < 5; t++)
            sc[t] = wave_sum64(q4 * kLp[t * 256 + col]) * 0.125f;
        float m = sc[0];
        #pragma unroll
        for (int t = 1; t < 5; t++) m = fmaxf(m, sc[t]);
        float p[5], sum = 0.f;
        #pragma unroll
        for (int t = 0; t < 5; t++) { p[t] = __expf(sc[t] - m); sum += p[t]; }
        float inv = 1.f / sum, cv = 0.f;
        #pragma unroll
        for (int t = 0; t < 5; t++) cv = fmaf(p[t], vLp[t * 256 + col], cv);
        ctxLp[col] = cv * inv;
    }
    __syncthreads();

    // out_proj
    {
        const int n = tid;
        float acc = 0.f;
        for (int k = 0; k < 256; k++)
            acc = fmaf(ctxLp[k], wopT[k * 256 + n], acc);
        featLp[n] = acc + bop[n];
    }
    __syncthreads();

    // heads: mean | logvar | belief-logits (coalesced whT)
    for (int j = tid; j < 320; j += 256) {
        float acc = 0.f;
        for (int k = 0; k < 256; k++)
            acc = fmaf(featLp[k], whT[k * 320 + j], acc);
        if (j < 128)       out[b * 128 + j] = acc + bm[j];
        else if (j < 256)  out[65536 + b * 128 + (j - 128)] = acc + blv[j - 128];
        else               belLp[j - 256] = acc + bb[j - 256];
    }
    __syncthreads();

    // belief softmax (wave 0)
    if (tid < 64) {
        float lg = belLp[tid];
        float m = wave_max64(lg);
        float e = __expf(lg - m);
        float s = wave_sum64(e);
        out[131072 + b * 64 + tid] = e / s;
    }
}

// ---------------------------------------------------------------------------
extern "C" void kernel_launch(void* const* d_in, const int* in_sizes, int n_in,
                              void* d_out, int out_size, void* d_ws, size_t ws_size,
                              hipStream_t stream) {
    const float* sig  = (const float*)d_in[0];
    const float* nact = (const float*)d_in[1];
    const float* w0   = (const float*)d_in[2];
    const float* as0  = (const float*)d_in[3];
    const float* ad0  = (const float*)d_in[4];
    const float* b0   = (const float*)d_in[5];
    const float* w1   = (const float*)d_in[6];
    const float* as1  = (const float*)d_in[7];
    const float* ad1  = (const float*)d_in[8];
    const float* b1   = (const float*)d_in[9];
    const float* wip  = (const float*)d_in[10];
    const float* bip  = (const float*)d_in[11];
    const float* wop  = (const float*)d_in[12];
    const float* bop  = (const float*)d_in[13];
    const float* wm   = (const float*)d_in[14];
    const float* bm   = (const float*)d_in[15];
    const float* wlv  = (const float*)d_in[16];
    const float* blv  = (const float*)d_in[17];
    const float* wb   = (const float*)d_in[18];
    const float* bb   = (const float*)d_in[19];
    // d_in[20] = edge_index (deterministic complete graph) — unused.

    // ws layout (floats): tws transposes + folds. ~1.7 MB.
    float* ws    = (float*)d_ws;
    float* tws   = ws;                 // 430080 total:
    float* W0sT  = tws;                //   16384
    float* W0aT  = tws + 16384;        //   4096
    float* W1T   = tws + 20480;        //   65536
    float* wipT  = tws + 86016;        //   196608
    float* wopT  = tws + 282624;       //   65536
    float* whT   = tws + 348160;       //   81920
    float* u1    = ws + 430080;        // 1024
    float* ud1   = ws + 431104;        // 1024
    float* pa0   = ws + 432128;        // 64
    float* pd0   = ws + 432192;        // 64

    k_pre  <<<1681, 256, 0, stream>>>(w0, w1, wip, wop, wm, wlv, wb,
                                      as0, ad0, as1, ad1,
                                      tws, u1, ud1, pa0, pd0);
    k_fused<<<512, 256, 0, stream>>>(sig, nact, W0sT, W0aT, W1T,
                                     u1, ud1, pa0, pd0, as0, ad0, b0, b1,
                                     wipT, bip, wopT, bop, whT, bm, blv, bb,
                                     (float*)d_out);
}

// Round 14
// 204.609 us; speedup vs baseline: 1.0348x; 1.0348x over previous
//
#include <hip/hip_runtime.h>
#include <hip/hip_bf16.h>

// T=5 B=512 NA=16 S=64 A=16 HID=64 H=4 FD=256 LAT=128 N=8192 FIN=80
// Inputs fp32, output fp32. edge graph = complete per 16-agent batch (ignored
// input). seq = x[::16] (dst agent-0 only). attention query only at t=4.
//
// R14 vs R13 (211.7 us): fusion was a loss (stage2 at 1 b/block + serialized
// behind GAT). Revert to R12's 3-kernel split; rebuild k_gat as one block per
// (b,g) (2560 blocks, no serial 5-group loop): critical path /5, TLP x5.
// LDS trimmed to ~37 KB (4 blocks/CU): S[n] and x1[16] in registers, z
// overlays dead d region, strides 257. Cost: W1T re-read per group (L2-hit).
// k_pre / k_stage2 = R12 verbatim.

__device__ __forceinline__ float wave_sum64(float v) {
    #pragma unroll
    for (int off = 32; off > 0; off >>= 1) v += __shfl_xor(v, off, 64);
    return v;
}
__device__ __forceinline__ float wave_max64(float v) {
    #pragma unroll
    for (int off = 32; off > 0; off >>= 1) v = fmaxf(v, __shfl_xor(v, off, 64));
    return v;
}

// ---------------- prologue: transposes + u1/ud1/pa0/pd0 (merged) ------------
__global__ __launch_bounds__(256) void k_pre(
    const float* __restrict__ w0, const float* __restrict__ w1,
    const float* __restrict__ wip, const float* __restrict__ wop,
    const float* __restrict__ wm, const float* __restrict__ wlv,
    const float* __restrict__ wb,
    const float* __restrict__ as0, const float* __restrict__ ad0,
    const float* __restrict__ as1, const float* __restrict__ ad1,
    float* __restrict__ tws,
    float* __restrict__ u1, float* __restrict__ ud1,
    float* __restrict__ pa0, float* __restrict__ pd0)
{
    const int tid = threadIdx.x;
    if (blockIdx.x < 1680) {
        int i = blockIdx.x * 256 + tid;          // 1680*256 = 430080 exact
        float v;
        if (i < 16384) {                         // W0sT[k][n] = w0[n][k]
            int k = i >> 8, n = i & 255;
            v = w0[n * 80 + k];
        } else if (i < 20480) {                  // W0aT[k][n] = w0[n][64+k]
            int j = i - 16384; int k = j >> 8, n = j & 255;
            v = w0[n * 80 + 64 + k];
        } else if (i < 86016) {                  // W1T[k][n] = w1[n][k]
            int j = i - 20480; int k = j >> 8, n = j & 255;
            v = w1[n * 256 + k];
        } else if (i < 282624) {                 // wipT[k][n'] = wip[n'][k]
            int j = i - 86016; int k = j / 768, n = j - k * 768;
            v = wip[n * 256 + k];
        } else if (i < 348160) {                 // wopT[k][n] = wop[n][k]
            int j = i - 282624; int k = j >> 8, n = j & 255;
            v = wop[n * 256 + k];
        } else {                                 // whT[k][j]: mean|logvar|belief
            int j = i - 348160; int k = j / 320, o = j - k * 320;
            if (o < 128)      v = wm[o * 256 + k];
            else if (o < 256) v = wlv[(o - 128) * 256 + k];
            else              v = wb[(o - 256) * 256 + k];
        }
        tws[i] = v;
        return;
    }
    // block 1680: u1[h][k] = sum_c as1[h][c]*w1[(h*64+c)][k]; ud1 with ad1
    for (int q = 0; q < 4; q++) {
        int idx = q * 256 + tid;                 // 1024
        int h = idx >> 8, k = idx & 255;
        float su = 0.f, sd = 0.f;
        for (int c = 0; c < 64; c++) {
            float wv = w1[(h * 64 + c) * 256 + k];
            su = fmaf(as1[h * 64 + c], wv, su);
            sd = fmaf(ad1[h * 64 + c], wv, sd);
        }
        u1[idx] = su; ud1[idx] = sd;
    }
    if (tid < 64) {
        int h = tid >> 4, k = tid & 15;
        float su = 0.f, sd = 0.f;
        for (int c = 0; c < 64; c++) {
            float wv = w0[(h * 64 + c) * 80 + 64 + k];
            su = fmaf(as0[h * 64 + c], wv, su);
            sd = fmaf(ad0[h * 64 + c], wv, sd);
        }
        pa0[tid] = su; pd0[tid] = sd;
    }
}

// ---------------- stage 1: fused 2-layer GAT, one block per (b,g) -----------
// 2560 blocks, 256 threads; thread n = output column; wave = head (n>>6).
// S[n] and x1[16] live in registers; z overlays d. ~36.9 KB LDS -> 4 blk/CU.
__global__ __launch_bounds__(256) void k_gat(
    const float* __restrict__ sig,   // (T,B,64)
    const float* __restrict__ nact,  // (T,B,256)
    const float* __restrict__ W0sT,  // [64][256]
    const float* __restrict__ W0aT,  // [16][256]
    const float* __restrict__ W1T,   // [256][256]
    const float* __restrict__ u1g, const float* __restrict__ ud1g,   // [4][256]
    const float* __restrict__ pa0g, const float* __restrict__ pd0g,  // [4][16]
    const float* __restrict__ as0, const float* __restrict__ ad0,
    const float* __restrict__ b0, const float* __restrict__ b1,
    float* __restrict__ seqf)        // (2560,256)
{
    __shared__ __align__(16) char smem[36832];
    float* actL   = (float*)(smem + 0);        // [16][16]
    float* u1L    = (float*)(smem + 1024);     // [4][257]
    float* ud1L   = (float*)(smem + 5136);     // [4][257]
    float* pa0L   = (float*)(smem + 9248);     // [64]
    float* pd0L   = (float*)(smem + 9504);     // [64]
    float* sSL    = (float*)(smem + 9760);     // [4]
    float* dSL    = (float*)(smem + 9776);     // [4]
    float* es0L   = (float*)(smem + 9792);     // [16][4]
    float* ed0L   = (float*)(smem + 10048);    // [16][4]
    float* a0L    = (float*)(smem + 10304);    // [4][16][16]
    float* dLa    = (float*)(smem + 14400);    // [4][16][16]; z [4][257] overlay
    float* zLa    = (float*)(smem + 14400);
    float* x1L    = (float*)(smem + 18512);    // [16][257]
    float* espL   = (float*)(smem + 34960);    // [16][4][4]
    float* edpL   = (float*)(smem + 35984);    // [4][4]
    float* es1L   = (float*)(smem + 36048);    // [16][4]
    float* edLx   = (float*)(smem + 36304);    // [4]
    float* alpha1L= (float*)(smem + 36320);    // [4][16]
    float* sigL   = (float*)(smem + 36576);    // [64]

    const int tid = threadIdx.x;
    const int bg = blockIdx.x;
    const int b = bg / 5, g = bg - b * 5;
    const int n = tid, w = tid >> 6, lane = tid & 63;

    // P1: loads
    if (tid < 64) sigL[tid] = sig[(g * 512 + b) * 64 + tid];
    actL[tid] = nact[(g * 512 + b) * 256 + tid];
    #pragma unroll
    for (int q = 0; q < 4; q++) {
        int idx = q * 256 + tid;
        int h = idx >> 8, k = idx & 255;
        u1L[h * 257 + k] = u1g[idx];
        ud1L[h * 257 + k] = ud1g[idx];
    }
    if (tid >= 64 && tid < 128) { pa0L[tid - 64] = pa0g[tid - 64]; pd0L[tid - 64] = pd0g[tid - 64]; }
    __syncthreads();

    // P2: S[n] (register) + head-wise sS/dS via wave reduce (wave w == head)
    float S = 0.f;
    for (int k = 0; k < 64; k++)
        S = fmaf(sigL[k], W0sT[k * 256 + n], S);
    {
        float ps = wave_sum64(S * as0[n]);
        float pd_ = wave_sum64(S * ad0[n]);
        if (lane == 0) { sSL[w] = ps; dSL[w] = pd_; }
    }
    __syncthreads();

    // P3: es0/ed0[m][h] = (m==0)*sS/dS[h] + act[m] . pa0/pd0[h]
    if (tid < 64) {
        int m = tid >> 2, h = tid & 3;
        float su = (m == 0) ? sSL[h] : 0.f;
        float sd = (m == 0) ? dSL[h] : 0.f;
        #pragma unroll
        for (int k = 0; k < 16; k++) {
            float av = actL[m * 16 + k];
            su = fmaf(av, pa0L[h * 16 + k], su);
            sd = fmaf(av, pd0L[h * 16 + k], sd);
        }
        es0L[m * 4 + h] = su; ed0L[m * 4 + h] = sd;
    }
    __syncthreads();

    // P4: alpha0[h][j][s]
    if (tid < 64) {
        int h = tid >> 4, j = tid & 15;
        float ej = ed0L[j * 4 + h];
        float e[16], m = -1e30f;
        #pragma unroll
        for (int s = 0; s < 16; s++) {
            float x = es0L[s * 4 + h] + ej;
            x = (x >= 0.f) ? x : 0.2f * x;
            e[s] = x; m = fmaxf(m, x);
        }
        float sum = 0.f;
        #pragma unroll
        for (int s = 0; s < 16; s++) { e[s] = __expf(e[s] - m); sum += e[s]; }
        float inv = 1.f / sum;
        #pragma unroll
        for (int s = 0; s < 16; s++) a0L[h * 256 + j * 16 + s] = e[s] * inv;
    }
    __syncthreads();

    // P5: d[h][j][k] = sum_s alpha0[h][j][s] * act[s][k]
    #pragma unroll
    for (int q = 0; q < 4; q++) {
        int idx = q * 256 + tid;
        int h = idx >> 8, j = (idx >> 4) & 15, k = idx & 15;
        float a = 0.f;
        #pragma unroll
        for (int s = 0; s < 16; s++)
            a = fmaf(a0L[h * 256 + j * 16 + s], actL[s * 16 + k], a);
        dLa[h * 256 + j * 16 + k] = a;
    }
    __syncthreads();

    // P6: x1[j] in registers; store to x1L for es1/z phases
    float x1r[16];
    {
        const int h = w;
        float b0v = b0[n];
        #pragma unroll
        for (int j = 0; j < 16; j++)
            x1r[j] = fmaf(a0L[h * 256 + j * 16], S, b0v);
        #pragma unroll
        for (int k = 0; k < 16; k++) {
            float wv = W0aT[k * 256 + n];
            #pragma unroll
            for (int j = 0; j < 16; j++)
                x1r[j] = fmaf(dLa[h * 256 + j * 16 + k], wv, x1r[j]);
        }
        #pragma unroll
        for (int j = 0; j < 16; j++) {
            x1r[j] = fmaxf(x1r[j], 0.f);
            x1L[j * 257 + n] = x1r[j];
        }
    }
    __syncthreads();

    // P7: es1[m][h] partials over k (p-split); ed1[h] from x1[0]
    {
        int m = tid >> 4, h = (tid >> 2) & 3, p = tid & 3;
        float a = 0.f;
        for (int kk = 0; kk < 64; kk++) {
            int k = kk * 4 + p;
            a = fmaf(x1L[m * 257 + k], u1L[h * 257 + k], a);
        }
        espL[m * 16 + h * 4 + p] = a;
        if (m == 0) {
            float ad = 0.f;
            for (int kk = 0; kk < 64; kk++) {
                int k = kk * 4 + p;
                ad = fmaf(x1L[k], ud1L[h * 257 + k], ad);
            }
            edpL[h * 4 + p] = ad;
        }
    }
    __syncthreads();
    if (tid < 64) {
        int m = tid >> 2, h = tid & 3;
        const float* e = espL + m * 16 + h * 4;
        es1L[m * 4 + h] = e[0] + e[1] + e[2] + e[3];
    }
    if (tid < 4)
        edLx[tid] = edpL[tid * 4] + edpL[tid * 4 + 1] + edpL[tid * 4 + 2] + edpL[tid * 4 + 3];
    __syncthreads();

    // P8: alpha1[h][s] (dst agent 0)
    if (tid < 4) {
        int h = tid;
        float ej = edLx[h];
        float e[16], m = -1e30f;
        #pragma unroll
        for (int s = 0; s < 16; s++) {
            float x = es1L[s * 4 + h] + ej;
            x = (x >= 0.f) ? x : 0.2f * x;
            e[s] = x; m = fmaxf(m, x);
        }
        float sum = 0.f;
        #pragma unroll
        for (int s = 0; s < 16; s++) { e[s] = __expf(e[s] - m); sum += e[s]; }
        float inv = 1.f / sum;
        #pragma unroll
        for (int s = 0; s < 16; s++) alpha1L[h * 16 + s] = e[s] * inv;
    }
    __syncthreads();

    // P9: z[h][k] = sum_s alpha1[h][s] * x1[s][k]  (thread k; overlay on d)
    {
        const int k = tid;
        float xv[16];
        #pragma unroll
        for (int s = 0; s < 16; s++) xv[s] = x1L[s * 257 + k];
        #pragma unroll
        for (int h = 0; h < 4; h++) {
            float zv = 0.f;
            #pragma unroll
            for (int s = 0; s < 16; s++)
                zv = fmaf(alpha1L[h * 16 + s], xv[s], zv);
            zLa[h * 257 + k] = zv;
        }
    }
    __syncthreads();

    // P10: seq[bg][n] = relu(z[h(n)] . W1T[:,n] + b1[n])
    {
        const int h = w;
        float acc = b1[n];
        for (int k = 0; k < 256; k++)
            acc = fmaf(zLa[h * 257 + k], W1T[k * 256 + n], acc);
        seqf[bg * 256 + n] = fmaxf(acc, 0.f);
    }
}

// ---------------- stage 2: qkv + attention + out_proj + heads (R12) ---------
__global__ __launch_bounds__(768) void k_stage2(
    const float* __restrict__ seqf,  // (2560,256)
    const float* __restrict__ wipT,  // [256][768]
    const float* __restrict__ bip,
    const float* __restrict__ wopT,  // [256][256]
    const float* __restrict__ bop,
    const float* __restrict__ whT,   // [256][320]
    const float* __restrict__ bm, const float* __restrict__ blv,
    const float* __restrict__ bb,
    float* __restrict__ out)
{
    __shared__ float sseq[2][5][256];
    __shared__ float kL[2][5][256], vL[2][5][256], qL[2][256];
    __shared__ float ctxL[2][256], featL[2][256];
    __shared__ float beliefL[2][64];
    const int tid = threadIdx.x;
    const int b0 = blockIdx.x * 2;

    {   // flat copy (batch boundary at 1280)
        float* sflat = &sseq[0][0][0];
        for (int i = tid; i < 2560; i += 768)
            sflat[i] = seqf[b0 * 1280 + i];
    }
    __syncthreads();

    // qkv: kind 0 -> q (t=4, both gb); kind 1 -> k (10 accs); kind 2 -> v
    {
        const int kind = tid >> 8, n = tid & 255;
        if (kind == 0) {
            float a0 = 0.f, a1 = 0.f;
            for (int k = 0; k < 256; k++) {
                float wv = wipT[k * 768 + n];
                a0 = fmaf(sseq[0][4][k], wv, a0);
                a1 = fmaf(sseq[1][4][k], wv, a1);
            }
            float bv = bip[n];
            qL[0][n] = a0 + bv; qL[1][n] = a1 + bv;
        } else {
            const float* wcol = wipT + kind * 256 + n;     // stride 768
            float acc[2][5];
            #pragma unroll
            for (int gb = 0; gb < 2; gb++)
                #pragma unroll
                for (int t = 0; t < 5; t++) acc[gb][t] = 0.f;
            for (int k = 0; k < 256; k++) {
                float wv = wcol[k * 768];
                #pragma unroll
                for (int gb = 0; gb < 2; gb++) {
                    #pragma unroll
                    for (int t = 0; t < 5; t++)
                        acc[gb][t] = fmaf(sseq[gb][t][k], wv, acc[gb][t]);
                }
            }
            float bv = bip[kind * 256 + n];
            float* dst = (kind == 1) ? &kL[0][0][0] : &vL[0][0][0];
            #pragma unroll
            for (int gb = 0; gb < 2; gb++)
                #pragma unroll
                for (int t = 0; t < 5; t++)
                    dst[gb * 1280 + t * 256 + n] = acc[gb][t] + bv;
        }
    }
    __syncthreads();

    // attention at q=4 (causal mask constant -> cancels)
    if (tid < 512) {
        const int gb = tid >> 8, col = tid & 255;
        float q4 = qL[gb][col];
        float sc[5];
        #pragma unroll
        for (int t = 0; t < 5; t++)
            sc[t] = wave_sum64(q4 * kL[gb][t][col]) * 0.125f;
        float m = sc[0];
        #pragma unroll
        for (int t = 1; t < 5; t++) m = fmaxf(m, sc[t]);
        float p[5], sum = 0.f;
        #pragma unroll
        for (int t = 0; t < 5; t++) { p[t] = __expf(sc[t] - m); sum += p[t]; }
        float inv = 1.f / sum, cv = 0.f;
        #pragma unroll
        for (int t = 0; t < 5; t++) cv = fmaf(p[t], vL[gb][t][col], cv);
        ctxL[gb][col] = cv * inv;
    }
    __syncthreads();

    // out_proj
    if (tid < 512) {
        const int gb = tid >> 8, n = tid & 255;
        float acc = 0.f;
        for (int k = 0; k < 256; k++)
            acc = fmaf(ctxL[gb][k], wopT[k * 256 + n], acc);
        featL[gb][n] = acc + bop[n];
    }
    __syncthreads();

    // heads: j in [0,320) for both gb
    if (tid < 640) {
        const int gb = tid / 320, j = tid - gb * 320;
        float acc = 0.f;
        for (int k = 0; k < 256; k++)
            acc = fmaf(featL[gb][k], whT[k * 320 + j], acc);
        if (j < 128) {
            out[(b0 + gb) * 128 + j] = acc + bm[j];
        } else if (j < 256) {
            out[65536 + (b0 + gb) * 128 + (j - 128)] = acc + blv[j - 128];
        } else {
            beliefL[gb][j - 256] = acc + bb[j - 256];
        }
    }
    __syncthreads();

    // belief softmax: wave 0 -> gb 0, wave 1 -> gb 1
    if (tid < 128) {
        int gb = tid >> 6, lane = tid & 63;
        float lg = beliefL[gb][lane];
        float m = wave_max64(lg);
        float e = __expf(lg - m);
        float s = wave_sum64(e);
        out[131072 + (b0 + gb) * 64 + lane] = e / s;
    }
}

// ---------------------------------------------------------------------------
extern "C" void kernel_launch(void* const* d_in, const int* in_sizes, int n_in,
                              void* d_out, int out_size, void* d_ws, size_t ws_size,
                              hipStream_t stream) {
    const float* sig  = (const float*)d_in[0];
    const float* nact = (const float*)d_in[1];
    const float* w0   = (const float*)d_in[2];
    const float* as0  = (const float*)d_in[3];
    const float* ad0  = (const float*)d_in[4];
    const float* b0   = (const float*)d_in[5];
    const float* w1   = (const float*)d_in[6];
    const float* as1  = (const float*)d_in[7];
    const float* ad1  = (const float*)d_in[8];
    const float* b1   = (const float*)d_in[9];
    const float* wip  = (const float*)d_in[10];
    const float* bip  = (const float*)d_in[11];
    const float* wop  = (const float*)d_in[12];
    const float* bop  = (const float*)d_in[13];
    const float* wm   = (const float*)d_in[14];
    const float* bm   = (const float*)d_in[15];
    const float* wlv  = (const float*)d_in[16];
    const float* blv  = (const float*)d_in[17];
    const float* wb   = (const float*)d_in[18];
    const float* bb   = (const float*)d_in[19];
    // d_in[20] = edge_index (deterministic complete graph) — unused.

    // ws layout (floats): seqf + transposes + folds. ~4.35 MB
    float* ws    = (float*)d_ws;
    float* seqf  = ws;                 // 655360
    float* tws   = ws + 655360;        // 430080:
    float* W0sT  = tws;                //   16384
    float* W0aT  = tws + 16384;        //   4096
    float* W1T   = tws + 20480;        //   65536
    float* wipT  = tws + 86016;        //   196608
    float* wopT  = tws + 282624;       //   65536
    float* whT   = tws + 348160;       //   81920
    float* u1    = ws + 1085440;       // 1024
    float* ud1   = ws + 1086464;       // 1024
    float* pa0   = ws + 1087488;       // 64
    float* pd0   = ws + 1087552;       // 64

    k_pre   <<<1681, 256, 0, stream>>>(w0, w1, wip, wop, wm, wlv, wb,
                                       as0, ad0, as1, ad1,
                                       tws, u1, ud1, pa0, pd0);
    k_gat   <<<2560, 256, 0, stream>>>(sig, nact, W0sT, W0aT, W1T,
                                       u1, ud1, pa0, pd0, as0, ad0, b0, b1, seqf);
    k_stage2<<<256, 768, 0, stream>>>(seqf, wipT, bip, wopT, bop, whT,
                                      bm, blv, bb, (float*)d_out);
}

// Round 15
// 201.239 us; speedup vs baseline: 1.0521x; 1.0167x over previous
//
#include <hip/hip_runtime.h>
#include <hip/hip_bf16.h>

// T=5 B=512 NA=16 S=64 A=16 HID=64 H=4 FD=256 LAT=128 N=8192 FIN=80
// Inputs fp32, output fp32. edge graph = complete per 16-agent batch (ignored
// input). seq = x[::16] (dst agent-0 only). attention query only at t=4.
//
// R15 vs R14 (204.6 us; k_gat 58.7): R12 vs R14 proved k_gat is bound by
// per-CU LDS-instruction issue (~850 scalar ds_read_b32/thread; identical
// time under 5x TLP / 5x L2-traffic changes). This round cuts LDS instr
// ~2.5x: xl0/x1/z held in registers (d round-trip eliminated), b128
// broadcasts for act/a0/alpha1/z/sig, es1 phase remapped to contiguous
// per-lane chunks (stride 260 -> 2-way free banks). Same algebra (R10).
// k_pre / k_stage2 = R12 verbatim.

__device__ __forceinline__ float wave_sum64(float v) {
    #pragma unroll
    for (int off = 32; off > 0; off >>= 1) v += __shfl_xor(v, off, 64);
    return v;
}
__device__ __forceinline__ float wave_max64(float v) {
    #pragma unroll
    for (int off = 32; off > 0; off >>= 1) v = fmaxf(v, __shfl_xor(v, off, 64));
    return v;
}

// ---------------- prologue: transposes + u1/ud1/pa0/pd0 (merged) ------------
__global__ __launch_bounds__(256) void k_pre(
    const float* __restrict__ w0, const float* __restrict__ w1,
    const float* __restrict__ wip, const float* __restrict__ wop,
    const float* __restrict__ wm, const float* __restrict__ wlv,
    const float* __restrict__ wb,
    const float* __restrict__ as0, const float* __restrict__ ad0,
    const float* __restrict__ as1, const float* __restrict__ ad1,
    float* __restrict__ tws,
    float* __restrict__ u1, float* __restrict__ ud1,
    float* __restrict__ pa0, float* __restrict__ pd0)
{
    const int tid = threadIdx.x;
    if (blockIdx.x < 1680) {
        int i = blockIdx.x * 256 + tid;          // 1680*256 = 430080 exact
        float v;
        if (i < 16384) {                         // W0sT[k][n] = w0[n][k]
            int k = i >> 8, n = i & 255;
            v = w0[n * 80 + k];
        } else if (i < 20480) {                  // W0aT[k][n] = w0[n][64+k]
            int j = i - 16384; int k = j >> 8, n = j & 255;
            v = w0[n * 80 + 64 + k];
        } else if (i < 86016) {                  // W1T[k][n] = w1[n][k]
            int j = i - 20480; int k = j >> 8, n = j & 255;
            v = w1[n * 256 + k];
        } else if (i < 282624) {                 // wipT[k][n'] = wip[n'][k]
            int j = i - 86016; int k = j / 768, n = j - k * 768;
            v = wip[n * 256 + k];
        } else if (i < 348160) {                 // wopT[k][n] = wop[n][k]
            int j = i - 282624; int k = j >> 8, n = j & 255;
            v = wop[n * 256 + k];
        } else {                                 // whT[k][j]: mean|logvar|belief
            int j = i - 348160; int k = j / 320, o = j - k * 320;
            if (o < 128)      v = wm[o * 256 + k];
            else if (o < 256) v = wlv[(o - 128) * 256 + k];
            else              v = wb[(o - 256) * 256 + k];
        }
        tws[i] = v;
        return;
    }
    for (int q = 0; q < 4; q++) {
        int idx = q * 256 + tid;                 // 1024
        int h = idx >> 8, k = idx & 255;
        float su = 0.f, sd = 0.f;
        for (int c = 0; c < 64; c++) {
            float wv = w1[(h * 64 + c) * 256 + k];
            su = fmaf(as1[h * 64 + c], wv, su);
            sd = fmaf(ad1[h * 64 + c], wv, sd);
        }
        u1[idx] = su; ud1[idx] = sd;
    }
    if (tid < 64) {
        int h = tid >> 4, k = tid & 15;
        float su = 0.f, sd = 0.f;
        for (int c = 0; c < 64; c++) {
            float wv = w0[(h * 64 + c) * 80 + 64 + k];
            su = fmaf(as0[h * 64 + c], wv, su);
            sd = fmaf(ad0[h * 64 + c], wv, sd);
        }
        pa0[tid] = su; pd0[tid] = sd;
    }
}

// ---------------- stage 1: 2-layer GAT, one block per (b,g), register-heavy -
// 2560 blocks, 256 threads; thread n = column; wave w = head (n>>6).
// xl0 / x1 / z live in registers; LDS reads are b128 broadcasts. 37.2 KB LDS.
__global__ __launch_bounds__(256) void k_gat(
    const float* __restrict__ sig,   // (T,B,64)
    const float* __restrict__ nact,  // (T,B,256)
    const float* __restrict__ W0sT,  // [64][256]
    const float* __restrict__ W0aT,  // [16][256]
    const float* __restrict__ W1T,   // [256][256]
    const float* __restrict__ u1g, const float* __restrict__ ud1g,   // [4][256]
    const float* __restrict__ pa0g, const float* __restrict__ pd0g,  // [4][16]
    const float* __restrict__ as0, const float* __restrict__ ad0,
    const float* __restrict__ b0, const float* __restrict__ b1,
    float* __restrict__ seqf)        // (2560,256)
{
    __shared__ __align__(16) char smem[37168];
    float* actL    = (float*)(smem + 0);       // [16][16]
    float* sigL    = (float*)(smem + 1024);    // [64]
    float* u1L     = (float*)(smem + 1280);    // [4][260]
    float* ud1L    = (float*)(smem + 5440);    // [4][260]
    float* pa0L    = (float*)(smem + 9600);    // [64]
    float* pd0L    = (float*)(smem + 9856);    // [64]
    float* sSL     = (float*)(smem + 10112);   // [4]
    float* dSL     = (float*)(smem + 10128);   // [4]
    float* es0L    = (float*)(smem + 10144);   // [16][4]
    float* ed0L    = (float*)(smem + 10400);   // [16][4]
    float* espL    = (float*)(smem + 10656);   // [16][4][4]
    float* es1L    = (float*)(smem + 11680);   // [16][4]
    float* edpL    = (float*)(smem + 11936);   // [4][4]
    float* edL     = (float*)(smem + 12000);   // [4]
    float* alpha1L = (float*)(smem + 12016);   // [4][16] (16B aligned)
    float* a0L     = (float*)(smem + 12272);   // [4][16][16] (16B aligned)
    float* zL      = (float*)(smem + 16368);   // [4][260] (16B aligned)
    float* x1L     = (float*)(smem + 20528);   // [16][260] (16B aligned)

    const int tid = threadIdx.x;
    const int bg = blockIdx.x;
    const int b = bg / 5, g = bg - b * 5;
    const int n = tid, w = tid >> 6, lane = tid & 63;

    // P1: loads
    if (tid < 64) sigL[tid] = sig[(g * 512 + b) * 64 + tid];
    actL[tid] = nact[(g * 512 + b) * 256 + tid];
    #pragma unroll
    for (int q = 0; q < 4; q++) {
        int idx = q * 256 + tid;
        int h = idx >> 8, k = idx & 255;
        u1L[h * 260 + k] = u1g[idx];
        ud1L[h * 260 + k] = ud1g[idx];
    }
    if (tid >= 64 && tid < 128) {
        pa0L[tid - 64] = pa0g[tid - 64];
        pd0L[tid - 64] = pd0g[tid - 64];
    }
    __syncthreads();

    // P2: S[n] in register (b128 sig broadcasts) + head sS/dS wave-reduce
    float S = 0.f;
    {
        const float4* sig4 = (const float4*)sigL;
        #pragma unroll 4
        for (int i = 0; i < 16; i++) {
            float4 sv = sig4[i];
            S = fmaf(sv.x, W0sT[(i * 4 + 0) * 256 + n], S);
            S = fmaf(sv.y, W0sT[(i * 4 + 1) * 256 + n], S);
            S = fmaf(sv.z, W0sT[(i * 4 + 2) * 256 + n], S);
            S = fmaf(sv.w, W0sT[(i * 4 + 3) * 256 + n], S);
        }
        float ps = wave_sum64(S * as0[n]);
        float pd_ = wave_sum64(S * ad0[n]);
        if (lane == 0) { sSL[w] = ps; dSL[w] = pd_; }
    }
    __syncthreads();

    // P3: es0/ed0[m][h] = (m==0)*sS/dS[h] + act[m] . pa0/pd0[h]
    if (tid < 64) {
        int m = tid >> 2, h = tid & 3;
        float su = (m == 0) ? sSL[h] : 0.f;
        float sd = (m == 0) ? dSL[h] : 0.f;
        #pragma unroll
        for (int k = 0; k < 16; k++) {
            float av = actL[m * 16 + k];
            su = fmaf(av, pa0L[h * 16 + k], su);
            sd = fmaf(av, pd0L[h * 16 + k], sd);
        }
        es0L[m * 4 + h] = su; ed0L[m * 4 + h] = sd;
    }
    __syncthreads();

    // P4: alpha0[h][j][s] (b128 stores)
    if (tid < 64) {
        int h = tid >> 4, j = tid & 15;
        float ej = ed0L[j * 4 + h];
        float e[16], m = -1e30f;
        #pragma unroll
        for (int s = 0; s < 16; s++) {
            float x = es0L[s * 4 + h] + ej;
            x = (x >= 0.f) ? x : 0.2f * x;
            e[s] = x; m = fmaxf(m, x);
        }
        float sum = 0.f;
        #pragma unroll
        for (int s = 0; s < 16; s++) { e[s] = __expf(e[s] - m); sum += e[s]; }
        float inv = 1.f / sum;
        float4* a04 = (float4*)(a0L + h * 256 + j * 16);
        #pragma unroll
        for (int s4 = 0; s4 < 4; s4++)
            a04[s4] = make_float4(e[s4 * 4] * inv, e[s4 * 4 + 1] * inv,
                                  e[s4 * 4 + 2] * inv, e[s4 * 4 + 3] * inv);
    }
    __syncthreads();

    // P56: xl0r[s] = (s==0)*S + act[s].W0aT[:,n] (regs); x1r[j] via b128 a0
    float x1r[16];
    {
        const int h = w;
        float wr[16];
        #pragma unroll
        for (int k = 0; k < 16; k++) wr[k] = W0aT[k * 256 + n];
        const float4* act4 = (const float4*)actL;
        float xl0r[16];
        #pragma unroll
        for (int s = 0; s < 16; s++) {
            float a = 0.f;
            #pragma unroll
            for (int q = 0; q < 4; q++) {
                float4 av = act4[s * 4 + q];
                a = fmaf(av.x, wr[q * 4 + 0], a);
                a = fmaf(av.y, wr[q * 4 + 1], a);
                a = fmaf(av.z, wr[q * 4 + 2], a);
                a = fmaf(av.w, wr[q * 4 + 3], a);
            }
            xl0r[s] = a;
        }
        xl0r[0] += S;
        const float b0v = b0[n];
        const float4* a04 = (const float4*)(a0L + h * 256);
        #pragma unroll
        for (int j = 0; j < 16; j++) {
            float acc = b0v;
            #pragma unroll
            for (int s4 = 0; s4 < 4; s4++) {
                float4 a4 = a04[j * 4 + s4];          // broadcast b128
                acc = fmaf(a4.x, xl0r[s4 * 4 + 0], acc);
                acc = fmaf(a4.y, xl0r[s4 * 4 + 1], acc);
                acc = fmaf(a4.z, xl0r[s4 * 4 + 2], acc);
                acc = fmaf(a4.w, xl0r[s4 * 4 + 3], acc);
            }
            x1r[j] = fmaxf(acc, 0.f);
            x1L[j * 260 + n] = x1r[j];
        }
    }
    __syncthreads();

    // P7: es1 partials; thread = (m=tid&15, h=(tid>>4)&3, chunk p=wave)
    {
        const int m = tid & 15, h = (tid >> 4) & 3, p = tid >> 6;
        const float4* x4p = (const float4*)(x1L + m * 260 + p * 64);
        const float4* u4p = (const float4*)(u1L + h * 260 + p * 64);
        float a = 0.f;
        #pragma unroll
        for (int i = 0; i < 16; i++) {
            float4 xv = x4p[i], uv = u4p[i];
            a = fmaf(xv.x, uv.x, a);
            a = fmaf(xv.y, uv.y, a);
            a = fmaf(xv.z, uv.z, a);
            a = fmaf(xv.w, uv.w, a);
        }
        espL[m * 16 + h * 4 + p] = a;
        if (m == 0) {
            const float4* ud4p = (const float4*)(ud1L + h * 260 + p * 64);
            float ad = 0.f;
            #pragma unroll
            for (int i = 0; i < 16; i++) {
                float4 xv = x4p[i], uv = ud4p[i];
                ad = fmaf(xv.x, uv.x, ad);
                ad = fmaf(xv.y, uv.y, ad);
                ad = fmaf(xv.z, uv.z, ad);
                ad = fmaf(xv.w, uv.w, ad);
            }
            edpL[h * 4 + p] = ad;
        }
    }
    __syncthreads();
    if (tid < 64) {
        int m = tid >> 2, h = tid & 3;
        const float* e = espL + m * 16 + h * 4;
        es1L[m * 4 + h] = e[0] + e[1] + e[2] + e[3];
    }
    if (tid < 4)
        edL[tid] = edpL[tid * 4] + edpL[tid * 4 + 1] + edpL[tid * 4 + 2] + edpL[tid * 4 + 3];
    __syncthreads();

    // P8: alpha1[h][s] (dst agent 0)
    if (tid < 4) {
        int h = tid;
        float ej = edL[h];
        float e[16], m = -1e30f;
        #pragma unroll
        for (int s = 0; s < 16; s++) {
            float x = es1L[s * 4 + h] + ej;
            x = (x >= 0.f) ? x : 0.2f * x;
            e[s] = x; m = fmaxf(m, x);
        }
        float sum = 0.f;
        #pragma unroll
        for (int s = 0; s < 16; s++) { e[s] = __expf(e[s] - m); sum += e[s]; }
        float inv = 1.f / sum;
        #pragma unroll
        for (int s = 0; s < 16; s++) alpha1L[h * 16 + s] = e[s] * inv;
    }
    __syncthreads();

    // P9: z[h][n] = sum_s alpha1[h][s] * x1r[s]  (all in registers)
    {
        const float4* a14 = (const float4*)alpha1L;
        #pragma unroll
        for (int hh = 0; hh < 4; hh++) {
            float zv = 0.f;
            #pragma unroll
            for (int s4 = 0; s4 < 4; s4++) {
                float4 a4 = a14[hh * 4 + s4];         // broadcast b128
                zv = fmaf(a4.x, x1r[s4 * 4 + 0], zv);
                zv = fmaf(a4.y, x1r[s4 * 4 + 1], zv);
                zv = fmaf(a4.z, x1r[s4 * 4 + 2], zv);
                zv = fmaf(a4.w, x1r[s4 * 4 + 3], zv);
            }
            zL[hh * 260 + n] = zv;
        }
    }
    __syncthreads();

    // P10: seq[bg][n] = relu(z[h(n)] . W1T[:,n] + b1[n])  (b128 z broadcasts)
    {
        const float4* zh = (const float4*)(zL + w * 260);
        float acc = b1[n];
        #pragma unroll 8
        for (int i = 0; i < 64; i++) {
            float4 z4 = zh[i];
            acc = fmaf(z4.x, W1T[(i * 4 + 0) * 256 + n], acc);
            acc = fmaf(z4.y, W1T[(i * 4 + 1) * 256 + n], acc);
            acc = fmaf(z4.z, W1T[(i * 4 + 2) * 256 + n], acc);
            acc = fmaf(z4.w, W1T[(i * 4 + 3) * 256 + n], acc);
        }
        seqf[bg * 256 + n] = fmaxf(acc, 0.f);
    }
}

// ---------------- stage 2: qkv + attention + out_proj + heads (R12) ---------
__global__ __launch_bounds__(768) void k_stage2(
    const float* __restrict__ seqf,  // (2560,256)
    const float* __restrict__ wipT,  // [256][768]
    const float* __restrict__ bip,
    const float* __restrict__ wopT,  // [256][256]
    const float* __restrict__ bop,
    const float* __restrict__ whT,   // [256][320]
    const float* __restrict__ bm, const float* __restrict__ blv,
    const float* __restrict__ bb,
    float* __restrict__ out)
{
    __shared__ float sseq[2][5][256];
    __shared__ float kL[2][5][256], vL[2][5][256], qL[2][256];
    __shared__ float ctxL[2][256], featL[2][256];
    __shared__ float beliefL[2][64];
    const int tid = threadIdx.x;
    const int b0 = blockIdx.x * 2;

    {   // flat copy (batch boundary at 1280)
        float* sflat = &sseq[0][0][0];
        for (int i = tid; i < 2560; i += 768)
            sflat[i] = seqf[b0 * 1280 + i];
    }
    __syncthreads();

    // qkv: kind 0 -> q (t=4, both gb); kind 1 -> k; kind 2 -> v
    {
        const int kind = tid >> 8, n = tid & 255;
        if (kind == 0) {
            float a0 = 0.f, a1 = 0.f;
            for (int k = 0; k < 256; k++) {
                float wv = wipT[k * 768 + n];
                a0 = fmaf(sseq[0][4][k], wv, a0);
                a1 = fmaf(sseq[1][4][k], wv, a1);
            }
            float bv = bip[n];
            qL[0][n] = a0 + bv; qL[1][n] = a1 + bv;
        } else {
            const float* wcol = wipT + kind * 256 + n;     // stride 768
            float acc[2][5];
            #pragma unroll
            for (int gb = 0; gb < 2; gb++)
                #pragma unroll
                for (int t = 0; t < 5; t++) acc[gb][t] = 0.f;
            for (int k = 0; k < 256; k++) {
                float wv = wcol[k * 768];
                #pragma unroll
                for (int gb = 0; gb < 2; gb++) {
                    #pragma unroll
                    for (int t = 0; t < 5; t++)
                        acc[gb][t] = fmaf(sseq[gb][t][k], wv, acc[gb][t]);
                }
            }
            float bv = bip[kind * 256 + n];
            float* dst = (kind == 1) ? &kL[0][0][0] : &vL[0][0][0];
            #pragma unroll
            for (int gb = 0; gb < 2; gb++)
                #pragma unroll
                for (int t = 0; t < 5; t++)
                    dst[gb * 1280 + t * 256 + n] = acc[gb][t] + bv;
        }
    }
    __syncthreads();

    // attention at q=4 (causal mask constant -> cancels)
    if (tid < 512) {
        const int gb = tid >> 8, col = tid & 255;
        float q4 = qL[gb][col];
        float sc[5];
        #pragma unroll
        for (int t = 0; t < 5; t++)
            sc[t] = wave_sum64(q4 * kL[gb][t][col]) * 0.125f;
        float m = sc[0];
        #pragma unroll
        for (int t = 1; t < 5; t++) m = fmaxf(m, sc[t]);
        float p[5], sum = 0.f;
        #pragma unroll
        for (int t = 0; t < 5; t++) { p[t] = __expf(sc[t] - m); sum += p[t]; }
        float inv = 1.f / sum, cv = 0.f;
        #pragma unroll
        for (int t = 0; t < 5; t++) cv = fmaf(p[t], vL[gb][t][col], cv);
        ctxL[gb][col] = cv * inv;
    }
    __syncthreads();

    // out_proj
    if (tid < 512) {
        const int gb = tid >> 8, n = tid & 255;
        float acc = 0.f;
        for (int k = 0; k < 256; k++)
            acc = fmaf(ctxL[gb][k], wopT[k * 256 + n], acc);
        featL[gb][n] = acc + bop[n];
    }
    __syncthreads();

    // heads: j in [0,320) for both gb
    if (tid < 640) {
        const int gb = tid / 320, j = tid - gb * 320;
        float acc = 0.f;
        for (int k = 0; k < 256; k++)
            acc = fmaf(featL[gb][k], whT[k * 320 + j], acc);
        if (j < 128) {
            out[(b0 + gb) * 128 + j] = acc + bm[j];
        } else if (j < 256) {
            out[65536 + (b0 + gb) * 128 + (j - 128)] = acc + blv[j - 128];
        } else {
            beliefL[gb][j - 256] = acc + bb[j - 256];
        }
    }
    __syncthreads();

    // belief softmax: wave 0 -> gb 0, wave 1 -> gb 1
    if (tid < 128) {
        int gb = tid >> 6, lane = tid & 63;
        float lg = beliefL[gb][lane];
        float m = wave_max64(lg);
        float e = __expf(lg - m);
        float s = wave_sum64(e);
        out[131072 + (b0 + gb) * 64 + lane] = e / s;
    }
}

// ---------------------------------------------------------------------------
extern "C" void kernel_launch(void* const* d_in, const int* in_sizes, int n_in,
                              void* d_out, int out_size, void* d_ws, size_t ws_size,
                              hipStream_t stream) {
    const float* sig  = (const float*)d_in[0];
    const float* nact = (const float*)d_in[1];
    const float* w0   = (const float*)d_in[2];
    const float* as0  = (const float*)d_in[3];
    const float* ad0  = (const float*)d_in[4];
    const float* b0   = (const float*)d_in[5];
    const float* w1   = (const float*)d_in[6];
    const float* as1  = (const float*)d_in[7];
    const float* ad1  = (const float*)d_in[8];
    const float* b1   = (const float*)d_in[9];
    const float* wip  = (const float*)d_in[10];
    const float* bip  = (const float*)d_in[11];
    const float* wop  = (const float*)d_in[12];
    const float* bop  = (const float*)d_in[13];
    const float* wm   = (const float*)d_in[14];
    const float* bm   = (const float*)d_in[15];
    const float* wlv  = (const float*)d_in[16];
    const float* blv  = (const float*)d_in[17];
    const float* wb   = (const float*)d_in[18];
    const float* bb   = (const float*)d_in[19];
    // d_in[20] = edge_index (deterministic complete graph) — unused.

    // ws layout (floats): seqf + transposes + folds. ~4.35 MB
    float* ws    = (float*)d_ws;
    float* seqf  = ws;                 // 655360
    float* tws   = ws + 655360;        // 430080:
    float* W0sT  = tws;                //   16384
    float* W0aT  = tws + 16384;        //   4096
    float* W1T   = tws + 20480;        //   65536
    float* wipT  = tws + 86016;        //   196608
    float* wopT  = tws + 282624;       //   65536
    float* whT   = tws + 348160;       //   81920
    float* u1    = ws + 1085440;       // 1024
    float* ud1   = ws + 1086464;       // 1024
    float* pa0   = ws + 1087488;       // 64
    float* pd0   = ws + 1087552;       // 64

    k_pre   <<<1681, 256, 0, stream>>>(w0, w1, wip, wop, wm, wlv, wb,
                                       as0, ad0, as1, ad1,
                                       tws, u1, ud1, pa0, pd0);
    k_gat   <<<2560, 256, 0, stream>>>(sig, nact, W0sT, W0aT, W1T,
                                       u1, ud1, pa0, pd0, as0, ad0, b0, b1, seqf);
    k_stage2<<<256, 768, 0, stream>>>(seqf, wipT, bip, wopT, bop, whT,
                                      bm, blv, bb, (float*)d_out);
}

// Round 16
// 199.833 us; speedup vs baseline: 1.0595x; 1.0070x over previous
//
#include <hip/hip_runtime.h>
#include <hip/hip_bf16.h>

// T=5 B=512 NA=16 S=64 A=16 HID=64 H=4 FD=256 LAT=128 N=8192 FIN=80
// Inputs fp32, output fp32. edge graph = complete per 16-agent batch (ignored
// input). seq = x[::16] (dst agent-0 only). attention query only at t=4.
//
// R16 vs R15 (201.2 us; k_gat ~55): conflicts fixed (6.0M->0.4M) but time
// flat -> not LDS-issue-bound either. 59% idle with no pipe saturated points
// at the 9-barrier phase skeleton (3 phases use <=64 of 256 threads).
// This round: barriers 9 -> 5 via per-wave head ownership (sS/dS in regs --
// wave_sum64 leaves sum in all lanes; es0/alpha0 computed wave-locally;
// es1+alpha1 in one wave-0 wave-synchronous region) + explicit 16-deep
// global-load batching in P2/P10. Same algebra (R10). k_pre/k_stage2 = R12.

__device__ __forceinline__ float wave_sum64(float v) {
    #pragma unroll
    for (int off = 32; off > 0; off >>= 1) v += __shfl_xor(v, off, 64);
    return v;
}
__device__ __forceinline__ float wave_max64(float v) {
    #pragma unroll
    for (int off = 32; off > 0; off >>= 1) v = fmaxf(v, __shfl_xor(v, off, 64));
    return v;
}

// ---------------- prologue: transposes + u1/ud1/pa0/pd0 (merged) ------------
__global__ __launch_bounds__(256) void k_pre(
    const float* __restrict__ w0, const float* __restrict__ w1,
    const float* __restrict__ wip, const float* __restrict__ wop,
    const float* __restrict__ wm, const float* __restrict__ wlv,
    const float* __restrict__ wb,
    const float* __restrict__ as0, const float* __restrict__ ad0,
    const float* __restrict__ as1, const float* __restrict__ ad1,
    float* __restrict__ tws,
    float* __restrict__ u1, float* __restrict__ ud1,
    float* __restrict__ pa0, float* __restrict__ pd0)
{
    const int tid = threadIdx.x;
    if (blockIdx.x < 1680) {
        int i = blockIdx.x * 256 + tid;          // 1680*256 = 430080 exact
        float v;
        if (i < 16384) {                         // W0sT[k][n] = w0[n][k]
            int k = i >> 8, n = i & 255;
            v = w0[n * 80 + k];
        } else if (i < 20480) {                  // W0aT[k][n] = w0[n][64+k]
            int j = i - 16384; int k = j >> 8, n = j & 255;
            v = w0[n * 80 + 64 + k];
        } else if (i < 86016) {                  // W1T[k][n] = w1[n][k]
            int j = i - 20480; int k = j >> 8, n = j & 255;
            v = w1[n * 256 + k];
        } else if (i < 282624) {                 // wipT[k][n'] = wip[n'][k]
            int j = i - 86016; int k = j / 768, n = j - k * 768;
            v = wip[n * 256 + k];
        } else if (i < 348160) {                 // wopT[k][n] = wop[n][k]
            int j = i - 282624; int k = j >> 8, n = j & 255;
            v = wop[n * 256 + k];
        } else {                                 // whT[k][j]: mean|logvar|belief
            int j = i - 348160; int k = j / 320, o = j - k * 320;
            if (o < 128)      v = wm[o * 256 + k];
            else if (o < 256) v = wlv[(o - 128) * 256 + k];
            else              v = wb[(o - 256) * 256 + k];
        }
        tws[i] = v;
        return;
    }
    for (int q = 0; q < 4; q++) {
        int idx = q * 256 + tid;                 // 1024
        int h = idx >> 8, k = idx & 255;
        float su = 0.f, sd = 0.f;
        for (int c = 0; c < 64; c++) {
            float wv = w1[(h * 64 + c) * 256 + k];
            su = fmaf(as1[h * 64 + c], wv, su);
            sd = fmaf(ad1[h * 64 + c], wv, sd);
        }
        u1[idx] = su; ud1[idx] = sd;
    }
    if (tid < 64) {
        int h = tid >> 4, k = tid & 15;
        float su = 0.f, sd = 0.f;
        for (int c = 0; c < 64; c++) {
            float wv = w0[(h * 64 + c) * 80 + 64 + k];
            su = fmaf(as0[h * 64 + c], wv, su);
            sd = fmaf(ad0[h * 64 + c], wv, sd);
        }
        pa0[tid] = su; pd0[tid] = sd;
    }
}

// ---------------- stage 1: 2-layer GAT, one block per (b,g), 5 barriers -----
// 2560 blocks, 256 threads; thread n = column; wave w = head (n>>6).
// es0/alpha0 computed wave-locally (wave-synchronous LDS); es1/alpha1 in one
// wave-0 region. xl0/x1/z math in registers, b128 LDS broadcasts, 16-deep
// batched global loads in P2/P10. 37.1 KB LDS -> 4 blocks/CU.
__global__ __launch_bounds__(256, 4) void k_gat(
    const float* __restrict__ sig,   // (T,B,64)
    const float* __restrict__ nact,  // (T,B,256)
    const float* __restrict__ W0sT,  // [64][256]
    const float* __restrict__ W0aT,  // [16][256]
    const float* __restrict__ W1T,   // [256][256]
    const float* __restrict__ u1g, const float* __restrict__ ud1g,   // [4][256]
    const float* __restrict__ pa0g, const float* __restrict__ pd0g,  // [4][16]
    const float* __restrict__ as0, const float* __restrict__ ad0,
    const float* __restrict__ b0, const float* __restrict__ b1,
    float* __restrict__ seqf)        // (2560,256)
{
    __shared__ __align__(16) char smem[37120];
    float* actL    = (float*)(smem + 0);       // [16][16]
    float* sigL    = (float*)(smem + 1024);    // [64]
    float* u1L     = (float*)(smem + 1280);    // [4][260]
    float* ud1L    = (float*)(smem + 5440);    // [4][260]
    float* pa0L    = (float*)(smem + 9600);    // [64]
    float* pd0L    = (float*)(smem + 9856);    // [64]
    float* es0w    = (float*)(smem + 10112);   // [4][16]  (per-wave)
    float* ed0w    = (float*)(smem + 10368);   // [4][16]
    float* espL    = (float*)(smem + 10624);   // [16][4][4]
    float* es1L    = (float*)(smem + 11648);   // [16][4]
    float* edpL    = (float*)(smem + 11904);   // [4][4]
    float* alpha1L = (float*)(smem + 11968);   // [4][16]
    float* a0L     = (float*)(smem + 12224);   // [4][16][16]
    float* zL      = (float*)(smem + 16320);   // [4][260]
    float* x1L     = (float*)(smem + 20480);   // [16][260]

    const int tid = threadIdx.x;
    const int bg = blockIdx.x;
    const int b = bg / 5, g = bg - b * 5;
    const int n = tid, w = tid >> 6, lane = tid & 63;

    // P1: loads
    if (tid < 64) sigL[tid] = sig[(g * 512 + b) * 64 + tid];
    actL[tid] = nact[(g * 512 + b) * 256 + tid];
    #pragma unroll
    for (int q = 0; q < 4; q++) {
        int idx = q * 256 + tid;
        int h = idx >> 8, k = idx & 255;
        u1L[h * 260 + k] = u1g[idx];
        ud1L[h * 260 + k] = ud1g[idx];
    }
    if (tid >= 64 && tid < 128) {
        pa0L[tid - 64] = pa0g[tid - 64];
        pd0L[tid - 64] = pd0g[tid - 64];
    }
    __syncthreads();                                       // barrier 1

    // P2: S[n] in register (16-deep batched W0sT loads); sS/dS in ALL lanes
    float S = 0.f;
    {
        const float4* sig4 = (const float4*)sigL;
        #pragma unroll
        for (int i = 0; i < 4; i++) {
            float wv[16];
            #pragma unroll
            for (int j = 0; j < 16; j++)
                wv[j] = W0sT[(i * 16 + j) * 256 + n];
            #pragma unroll
            for (int q = 0; q < 4; q++) {
                float4 sv = sig4[i * 4 + q];
                S = fmaf(wv[q * 4 + 0], sv.x, S);
                S = fmaf(wv[q * 4 + 1], sv.y, S);
                S = fmaf(wv[q * 4 + 2], sv.z, S);
                S = fmaf(wv[q * 4 + 3], sv.w, S);
            }
        }
    }
    const float sS = wave_sum64(S * as0[n]);   // full sum in every lane
    const float dS = wave_sum64(S * ad0[n]);

    // P3+P4 (wave-local, head w; no block barrier):
    // es0w[w][m] = (m==0)*sS + act[m].pa0[w]; alpha0 row for head w
    if (lane < 16) {
        const int m = lane;
        float su = (m == 0) ? sS : 0.f;
        float sd = (m == 0) ? dS : 0.f;
        const float4* act4 = (const float4*)(actL + m * 16);
        const float4* pa4  = (const float4*)(pa0L + w * 16);
        const float4* pd4  = (const float4*)(pd0L + w * 16);
        #pragma unroll
        for (int q = 0; q < 4; q++) {
            float4 av = act4[q], pv = pa4[q], dv = pd4[q];
            su = fmaf(av.x, pv.x, su); su = fmaf(av.y, pv.y, su);
            su = fmaf(av.z, pv.z, su); su = fmaf(av.w, pv.w, su);
            sd = fmaf(av.x, dv.x, sd); sd = fmaf(av.y, dv.y, sd);
            sd = fmaf(av.z, dv.z, sd); sd = fmaf(av.w, dv.w, sd);
        }
        es0w[w * 16 + m] = su;
        ed0w[w * 16 + m] = sd;
    }
    // wave-synchronous: same wave wrote es0w/ed0w, now reads them
    if (lane < 16) {
        const int j = lane;
        float ej = ed0w[w * 16 + j];
        float e[16], m = -1e30f;
        const float4* es4 = (const float4*)(es0w + w * 16);
        #pragma unroll
        for (int s4 = 0; s4 < 4; s4++) {
            float4 ev = es4[s4];
            float x;
            x = ev.x + ej; x = (x >= 0.f) ? x : 0.2f * x; e[s4*4+0] = x; m = fmaxf(m, x);
            x = ev.y + ej; x = (x >= 0.f) ? x : 0.2f * x; e[s4*4+1] = x; m = fmaxf(m, x);
            x = ev.z + ej; x = (x >= 0.f) ? x : 0.2f * x; e[s4*4+2] = x; m = fmaxf(m, x);
            x = ev.w + ej; x = (x >= 0.f) ? x : 0.2f * x; e[s4*4+3] = x; m = fmaxf(m, x);
        }
        float sum = 0.f;
        #pragma unroll
        for (int s = 0; s < 16; s++) { e[s] = __expf(e[s] - m); sum += e[s]; }
        float inv = 1.f / sum;
        float4* a04 = (float4*)(a0L + w * 256 + j * 16);
        #pragma unroll
        for (int s4 = 0; s4 < 4; s4++)
            a04[s4] = make_float4(e[s4 * 4] * inv, e[s4 * 4 + 1] * inv,
                                  e[s4 * 4 + 2] * inv, e[s4 * 4 + 3] * inv);
    }
    // a0L[w] written and consumed by wave w only -> still no block barrier

    // P56: xl0r[s] = (s==0)*S + act[s].W0aT[:,n]; x1r[j] via b128 a0L[w]
    float x1r[16];
    {
        float wr[16];
        #pragma unroll
        for (int k = 0; k < 16; k++) wr[k] = W0aT[k * 256 + n];
        const float4* act4 = (const float4*)actL;
        float xl0r[16];
        #pragma unroll
        for (int s = 0; s < 16; s++) {
            float a = 0.f;
            #pragma unroll
            for (int q = 0; q < 4; q++) {
                float4 av = act4[s * 4 + q];
                a = fmaf(av.x, wr[q * 4 + 0], a);
                a = fmaf(av.y, wr[q * 4 + 1], a);
                a = fmaf(av.z, wr[q * 4 + 2], a);
                a = fmaf(av.w, wr[q * 4 + 3], a);
            }
            xl0r[s] = a;
        }
        xl0r[0] += S;
        const float b0v = b0[n];
        const float4* a04 = (const float4*)(a0L + w * 256);
        #pragma unroll
        for (int j = 0; j < 16; j++) {
            float acc = b0v;
            #pragma unroll
            for (int s4 = 0; s4 < 4; s4++) {
                float4 a4 = a04[j * 4 + s4];          // broadcast b128
                acc = fmaf(a4.x, xl0r[s4 * 4 + 0], acc);
                acc = fmaf(a4.y, xl0r[s4 * 4 + 1], acc);
                acc = fmaf(a4.z, xl0r[s4 * 4 + 2], acc);
                acc = fmaf(a4.w, xl0r[s4 * 4 + 3], acc);
            }
            x1r[j] = fmaxf(acc, 0.f);
            x1L[j * 260 + n] = x1r[j];
        }
    }
    __syncthreads();                                       // barrier 2

    // P7: es1/ed1 partials; thread = (m=tid&15, h=(tid>>4)&3, chunk p=wave)
    {
        const int m = tid & 15, h = (tid >> 4) & 3, p = tid >> 6;
        const float4* x4p = (const float4*)(x1L + m * 260 + p * 64);
        const float4* u4p = (const float4*)(u1L + h * 260 + p * 64);
        float a = 0.f;
        #pragma unroll
        for (int i = 0; i < 16; i++) {
            float4 xv = x4p[i], uv = u4p[i];
            a = fmaf(xv.x, uv.x, a);
            a = fmaf(xv.y, uv.y, a);
            a = fmaf(xv.z, uv.z, a);
            a = fmaf(xv.w, uv.w, a);
        }
        espL[m * 16 + h * 4 + p] = a;
        if (m == 0) {
            const float4* ud4p = (const float4*)(ud1L + h * 260 + p * 64);
            float ad = 0.f;
            #pragma unroll
            for (int i = 0; i < 16; i++) {
                float4 xv = x4p[i], uv = ud4p[i];
                ad = fmaf(xv.x, uv.x, ad);
                ad = fmaf(xv.y, uv.y, ad);
                ad = fmaf(xv.z, uv.z, ad);
                ad = fmaf(xv.w, uv.w, ad);
            }
            edpL[h * 4 + p] = ad;
        }
    }
    __syncthreads();                                       // barrier 3

    // P8 (wave 0, wave-synchronous): es1 sums then alpha1
    if (w == 0) {
        {
            const int m = lane >> 2, h = lane & 3;
            const float* e = espL + m * 16 + h * 4;
            es1L[m * 4 + h] = e[0] + e[1] + e[2] + e[3];
        }
        if (lane < 4) {
            const int h = lane;
            float ej = edpL[h * 4] + edpL[h * 4 + 1] + edpL[h * 4 + 2] + edpL[h * 4 + 3];
            float e[16], m = -1e30f;
            #pragma unroll
            for (int s = 0; s < 16; s++) {
                float x = es1L[s * 4 + h] + ej;
                x = (x >= 0.f) ? x : 0.2f * x;
                e[s] = x; m = fmaxf(m, x);
            }
            float sum = 0.f;
            #pragma unroll
            for (int s = 0; s < 16; s++) { e[s] = __expf(e[s] - m); sum += e[s]; }
            float inv = 1.f / sum;
            #pragma unroll
            for (int s = 0; s < 16; s++) alpha1L[h * 16 + s] = e[s] * inv;
        }
    }
    __syncthreads();                                       // barrier 4

    // P9: z[hh][n] = sum_s alpha1[hh][s] * x1r[s]  (x1 already in registers)
    {
        const float4* a14 = (const float4*)alpha1L;
        #pragma unroll
        for (int hh = 0; hh < 4; hh++) {
            float zv = 0.f;
            #pragma unroll
            for (int s4 = 0; s4 < 4; s4++) {
                float4 a4 = a14[hh * 4 + s4];         // broadcast b128
                zv = fmaf(a4.x, x1r[s4 * 4 + 0], zv);
                zv = fmaf(a4.y, x1r[s4 * 4 + 1], zv);
                zv = fmaf(a4.z, x1r[s4 * 4 + 2], zv);
                zv = fmaf(a4.w, x1r[s4 * 4 + 3], zv);
            }
            zL[hh * 260 + n] = zv;
        }
    }
    __syncthreads();                                       // barrier 5

    // P10: seq[bg][n] = relu(z[w] . W1T[:,n] + b1[n]); 16-deep batched loads
    {
        const float4* zh = (const float4*)(zL + w * 260);
        float acc = b1[n];
        for (int i = 0; i < 16; i++) {
            float wv[16];
            #pragma unroll
            for (int j = 0; j < 16; j++)
                wv[j] = W1T[(i * 16 + j) * 256 + n];
            #pragma unroll
            for (int q = 0; q < 4; q++) {
                float4 z4 = zh[i * 4 + q];
                acc = fmaf(wv[q * 4 + 0], z4.x, acc);
                acc = fmaf(wv[q * 4 + 1], z4.y, acc);
                acc = fmaf(wv[q * 4 + 2], z4.z, acc);
                acc = fmaf(wv[q * 4 + 3], z4.w, acc);
            }
        }
        seqf[bg * 256 + n] = fmaxf(acc, 0.f);
    }
}

// ---------------- stage 2: qkv + attention + out_proj + heads (R12) ---------
__global__ __launch_bounds__(768) void k_stage2(
    const float* __restrict__ seqf,  // (2560,256)
    const float* __restrict__ wipT,  // [256][768]
    const float* __restrict__ bip,
    const float* __restrict__ wopT,  // [256][256]
    const float* __restrict__ bop,
    const float* __restrict__ whT,   // [256][320]
    const float* __restrict__ bm, const float* __restrict__ blv,
    const float* __restrict__ bb,
    float* __restrict__ out)
{
    __shared__ float sseq[2][5][256];
    __shared__ float kL[2][5][256], vL[2][5][256], qL[2][256];
    __shared__ float ctxL[2][256], featL[2][256];
    __shared__ float beliefL[2][64];
    const int tid = threadIdx.x;
    const int b0 = blockIdx.x * 2;

    {   // flat copy (batch boundary at 1280)
        float* sflat = &sseq[0][0][0];
        for (int i = tid; i < 2560; i += 768)
            sflat[i] = seqf[b0 * 1280 + i];
    }
    __syncthreads();

    // qkv: kind 0 -> q (t=4, both gb); kind 1 -> k; kind 2 -> v
    {
        const int kind = tid >> 8, n = tid & 255;
        if (kind == 0) {
            float a0 = 0.f, a1 = 0.f;
            for (int k = 0; k < 256; k++) {
                float wv = wipT[k * 768 + n];
                a0 = fmaf(sseq[0][4][k], wv, a0);
                a1 = fmaf(sseq[1][4][k], wv, a1);
            }
            float bv = bip[n];
            qL[0][n] = a0 + bv; qL[1][n] = a1 + bv;
        } else {
            const float* wcol = wipT + kind * 256 + n;     // stride 768
            float acc[2][5];
            #pragma unroll
            for (int gb = 0; gb < 2; gb++)
                #pragma unroll
                for (int t = 0; t < 5; t++) acc[gb][t] = 0.f;
            for (int k = 0; k < 256; k++) {
                float wv = wcol[k * 768];
                #pragma unroll
                for (int gb = 0; gb < 2; gb++) {
                    #pragma unroll
                    for (int t = 0; t < 5; t++)
                        acc[gb][t] = fmaf(sseq[gb][t][k], wv, acc[gb][t]);
                }
            }
            float bv = bip[kind * 256 + n];
            float* dst = (kind == 1) ? &kL[0][0][0] : &vL[0][0][0];
            #pragma unroll
            for (int gb = 0; gb < 2; gb++)
                #pragma unroll
                for (int t = 0; t < 5; t++)
                    dst[gb * 1280 + t * 256 + n] = acc[gb][t] + bv;
        }
    }
    __syncthreads();

    // attention at q=4 (causal mask constant -> cancels)
    if (tid < 512) {
        const int gb = tid >> 8, col = tid & 255;
        float q4 = qL[gb][col];
        float sc[5];
        #pragma unroll
        for (int t = 0; t < 5; t++)
            sc[t] = wave_sum64(q4 * kL[gb][t][col]) * 0.125f;
        float m = sc[0];
        #pragma unroll
        for (int t = 1; t < 5; t++) m = fmaxf(m, sc[t]);
        float p[5], sum = 0.f;
        #pragma unroll
        for (int t = 0; t < 5; t++) { p[t] = __expf(sc[t] - m); sum += p[t]; }
        float inv = 1.f / sum, cv = 0.f;
        #pragma unroll
        for (int t = 0; t < 5; t++) cv = fmaf(p[t], vL[gb][t][col], cv);
        ctxL[gb][col] = cv * inv;
    }
    __syncthreads();

    // out_proj
    if (tid < 512) {
        const int gb = tid >> 8, n = tid & 255;
        float acc = 0.f;
        for (int k = 0; k < 256; k++)
            acc = fmaf(ctxL[gb][k], wopT[k * 256 + n], acc);
        featL[gb][n] = acc + bop[n];
    }
    __syncthreads();

    // heads: j in [0,320) for both gb
    if (tid < 640) {
        const int gb = tid / 320, j = tid - gb * 320;
        float acc = 0.f;
        for (int k = 0; k < 256; k++)
            acc = fmaf(featL[gb][k], whT[k * 320 + j], acc);
        if (j < 128) {
            out[(b0 + gb) * 128 + j] = acc + bm[j];
        } else if (j < 256) {
            out[65536 + (b0 + gb) * 128 + (j - 128)] = acc + blv[j - 128];
        } else {
            beliefL[gb][j - 256] = acc + bb[j - 256];
        }
    }
    __syncthreads();

    // belief softmax: wave 0 -> gb 0, wave 1 -> gb 1
    if (tid < 128) {
        int gb = tid >> 6, lane = tid & 63;
        float lg = beliefL[gb][lane];
        float m = wave_max64(lg);
        float e = __expf(lg - m);
        float s = wave_sum64(e);
        out[131072 + (b0 + gb) * 64 + lane] = e / s;
    }
}

// ---------------------------------------------------------------------------
extern "C" void kernel_launch(void* const* d_in, const int* in_sizes, int n_in,
                              void* d_out, int out_size, void* d_ws, size_t ws_size,
                              hipStream_t stream) {
    const float* sig  = (const float*)d_in[0];
    const float* nact = (const float*)d_in[1];
    const float* w0   = (const float*)d_in[2];
    const float* as0  = (const float*)d_in[3];
    const float* ad0  = (const float*)d_in[4];
    const float* b0   = (const float*)d_in[5];
    const float* w1   = (const float*)d_in[6];
    const float* as1  = (const float*)d_in[7];
    const float* ad1  = (const float*)d_in[8];
    const float* b1   = (const float*)d_in[9];
    const float* wip  = (const float*)d_in[10];
    const float* bip  = (const float*)d_in[11];
    const float* wop  = (const float*)d_in[12];
    const float* bop  = (const float*)d_in[13];
    const float* wm   = (const float*)d_in[14];
    const float* bm   = (const float*)d_in[15];
    const float* wlv  = (const float*)d_in[16];
    const float* blv  = (const float*)d_in[17];
    const float* wb   = (const float*)d_in[18];
    const float* bb   = (const float*)d_in[19];
    // d_in[20] = edge_index (deterministic complete graph) — unused.

    // ws layout (floats): seqf + transposes + folds. ~4.35 MB
    float* ws    = (float*)d_ws;
    float* seqf  = ws;                 // 655360
    float* tws   = ws + 655360;        // 430080:
    float* W0sT  = tws;                //   16384
    float* W0aT  = tws + 16384;        //   4096
    float* W1T   = tws + 20480;        //   65536
    float* wipT  = tws + 86016;        //   196608
    float* wopT  = tws + 282624;       //   65536
    float* whT   = tws + 348160;       //   81920
    float* u1    = ws + 1085440;       // 1024
    float* ud1   = ws + 1086464;       // 1024
    float* pa0   = ws + 1087488;       // 64
    float* pd0   = ws + 1087552;       // 64

    k_pre   <<<1681, 256, 0, stream>>>(w0, w1, wip, wop, wm, wlv, wb,
                                       as0, ad0, as1, ad1,
                                       tws, u1, ud1, pa0, pd0);
    k_gat   <<<2560, 256, 0, stream>>>(sig, nact, W0sT, W0aT, W1T,
                                       u1, ud1, pa0, pd0, as0, ad0, b0, b1, seqf);
    k_stage2<<<256, 768, 0, stream>>>(seqf, wipT, bip, wopT, bop, whT,
                                      bm, blv, bb, (float*)d_out);
}